// Round 1
// baseline (6057.770 us; speedup 1.0000x reference)
//
#include <hip/hip_runtime.h>
#include <hip/hip_fp16.h>

typedef _Float16 f16;
typedef _Float16 f16x2 __attribute__((ext_vector_type(2)));
typedef _Float16 f16x8 __attribute__((ext_vector_type(8)));
typedef float    f32x4 __attribute__((ext_vector_type(4)));

#if __has_builtin(__builtin_amdgcn_fdot2)
#define USE_FDOT2 1
#else
#define USE_FDOT2 0
#endif

__device__ __forceinline__ float dot2acc(unsigned int w, unsigned int h, float acc) {
#if USE_FDOT2
  return __builtin_amdgcn_fdot2(__builtin_bit_cast(f16x2, w),
                                __builtin_bit_cast(f16x2, h), acc, false);
#else
  f16x2 a = __builtin_bit_cast(f16x2, w);
  f16x2 b = __builtin_bit_cast(f16x2, h);
  return acc + (float)a.x * (float)b.x + (float)a.y * (float)b.y;
#endif
}

__device__ __forceinline__ float sigm(float x) { return 1.f / (1.f + __expf(-x)); }
__device__ __forceinline__ float reluf(float x) { return x > 0.f ? x : 0.f; }
__device__ __forceinline__ unsigned int packh2(float lo, float hi) {
  f16x2 v; v.x = (f16)lo; v.y = (f16)hi;
  return __builtin_bit_cast(unsigned int, v);
}

// ---------------- weight packing: f32 [K][N] -> uint (f16 pair along K) [K/2][N]
__global__ void pack_pairs(const float* __restrict__ src, unsigned int* __restrict__ dst, int N) {
  int j  = blockIdx.x * 256 + threadIdx.x;
  int k2 = blockIdx.y;
  if (j >= N) return;
  dst[k2 * N + j] = packh2(src[(2 * k2) * N + j], src[(2 * k2 + 1) * N + j]);
}

// ---------------- pack B for MFMA b-frag layout
// dst[((c*KF+kf)*64+L)*8+j] = B[kf*32 + (L>>4)*8 + j][c*16 + (L&15)]
template <int KF>
__global__ void pack_bsw(const float* __restrict__ B, f16* __restrict__ dst, int N) {
  int id = blockIdx.x * 256 + threadIdx.x;
  int total = KF * 32 * N;
  if (id >= total) return;
  int j  = id & 7;
  int L  = (id >> 3) & 63;
  int r  = id >> 9;
  int kf = r & (KF - 1);
  int c  = r / KF;
  int k  = kf * 32 + ((L >> 4) * 8) + j;
  int n  = c * 16 + (L & 15);
  dst[id] = (f16)B[k * N + n];
}

// ---------------- xW GEMM: C[M][N] = gather(emb, tok)[M][K] @ B[K][N] + bias, f16 out
// block: 256 thr (4 waves), 64 rows per block; wave w -> rows blk*64+w*16
template <int K, int KF, int N, int NC>
__global__ __launch_bounds__(256) void gemm_xw(const int* __restrict__ tok,
                                               const float* __restrict__ emb,
                                               const f16* __restrict__ Bsw,
                                               const float* __restrict__ bias,
                                               f16* __restrict__ C) {
  __shared__ int tokLds[64];
  __shared__ f16x8 bLds[8 * 64];
  const int tid = threadIdx.x;
  const int blk = blockIdx.x;
  if (tid < 64) tokLds[tid] = tok[blk * 64 + tid];
  __syncthreads();
  const int wave = tid >> 6, lane = tid & 63;
  const int quad = lane >> 4, l16 = lane & 15;
  const int m0 = wave * 16;

  f16x8 a[KF];
  {
    const int row = m0 + l16;
    const float* arow = emb + (long)tokLds[row] * K + quad * 8;
#pragma unroll
    for (int kf = 0; kf < KF; kf++) {
      float4 v0 = *(const float4*)(arow + kf * 32);
      float4 v1 = *(const float4*)(arow + kf * 32 + 4);
      f16x8 tv;
      tv[0] = (f16)v0.x; tv[1] = (f16)v0.y; tv[2] = (f16)v0.z; tv[3] = (f16)v0.w;
      tv[4] = (f16)v1.x; tv[5] = (f16)v1.y; tv[6] = (f16)v1.z; tv[7] = (f16)v1.w;
      a[kf] = tv;
    }
  }
  const long crow = (long)(blk * 64 + m0) * N;
  const f16x8* Bfrag = (const f16x8*)Bsw;
  for (int c = 0; c < NC; c++) {
    for (int i = tid; i < KF * 64; i += 256) bLds[i] = Bfrag[c * KF * 64 + i];
    __syncthreads();
    f32x4 acc = {0.f, 0.f, 0.f, 0.f};
#pragma unroll
    for (int kf = 0; kf < KF; kf++)
      acc = __builtin_amdgcn_mfma_f32_16x16x32_f16(a[kf], bLds[kf * 64 + lane], acc, 0, 0, 0);
    const int col = c * 16 + l16;
    const float bc = bias[col];
#pragma unroll
    for (int r = 0; r < 4; r++)
      C[crow + (long)(quad * 4 + r) * N + col] = (f16)(acc[r] + bc);
    __syncthreads();
  }
}

// ---------------- fused recurrent stacks: blocks 0..127 paragraph, 128..255 title
struct RecurArgs {
  const f16* xpW; const f16* xtW;
  const unsigned int *U0p, *W1p, *U1p, *W2p, *U2p;
  const unsigned int *U0t, *W1t, *U1t;
  const float *pl1_b, *pl2_b, *tl1_b;
  const float *pd0W, *pd0b, *pd1W, *pd1b, *pd2W, *pd2b;
  const float *td0W, *td0b, *td1W, *td1b, *td2W, *td2b;
  float* feat;
};

__global__ __launch_bounds__(1024) void recur_kernel(RecurArgs A) {
  __shared__ float zbuf[1024];
  __shared__ unsigned int h0p[128];
  __shared__ unsigned int h1p[64];
  __shared__ unsigned int h2p[32];
  __shared__ float hfin[64];
  const int tid = threadIdx.x;
  const int blk = blockIdx.x;

  if (blk < 128) {
    // ---------- paragraph sequence s ----------
    const int s = blk;
    if (tid < 128) h0p[tid] = 0u;
    if (tid < 64)  h1p[tid] = 0u;
    if (tid < 32)  h2p[tid] = 0u;
    float c0 = 0.f, c1 = 0.f, c2 = 0.f;
    const float b1r = (tid < 512) ? A.pl1_b[tid] : 0.f;
    const float b2r = (tid < 256) ? A.pl2_b[tid] : 0.f;
    const unsigned int* u0c = A.U0p + tid;
    const unsigned int* w1c = A.W1p + tid;
    const unsigned int* u1c = A.U1p + tid;
    const unsigned int* w2c = A.W2p + tid;
    const unsigned int* u2c = A.U2p + tid;
    const f16* xrow = A.xpW + (long)s * 512 * 1024;
    __syncthreads();
    for (int t = 0; t < 512; t++) {
      {
        float acc = (float)xrow[t * 1024 + tid];
#pragma unroll 8
        for (int k2 = 0; k2 < 128; k2++) acc = dot2acc(u0c[k2 * 1024], h0p[k2], acc);
        zbuf[tid] = acc;
      }
      __syncthreads();
      if (tid < 256) {
        float gi = sigm(zbuf[tid]);
        float gf = sigm(zbuf[256 + tid]);
        float gg = reluf(zbuf[512 + tid]);
        float go = sigm(zbuf[768 + tid]);
        c0 = gf * c0 + gi * gg;
        float h = go * reluf(c0);
        float hn = __shfl_xor(h, 1);
        if ((tid & 1) == 0) h0p[tid >> 1] = packh2(h, hn);
      }
      __syncthreads();
      if (tid < 512) {
        float acc = b1r;
#pragma unroll 8
        for (int k2 = 0; k2 < 128; k2++) acc = dot2acc(w1c[k2 * 512], h0p[k2], acc);
#pragma unroll 8
        for (int k2 = 0; k2 < 64; k2++)  acc = dot2acc(u1c[k2 * 512], h1p[k2], acc);
        zbuf[tid] = acc;
      }
      __syncthreads();
      if (tid < 128) {
        float gi = sigm(zbuf[tid]);
        float gf = sigm(zbuf[128 + tid]);
        float gg = reluf(zbuf[256 + tid]);
        float go = sigm(zbuf[384 + tid]);
        c1 = gf * c1 + gi * gg;
        float h = go * reluf(c1);
        float hn = __shfl_xor(h, 1);
        if ((tid & 1) == 0) h1p[tid >> 1] = packh2(h, hn);
      }
      __syncthreads();
      if (tid < 256) {
        float acc = b2r;
#pragma unroll 8
        for (int k2 = 0; k2 < 64; k2++) acc = dot2acc(w2c[k2 * 256], h1p[k2], acc);
#pragma unroll 8
        for (int k2 = 0; k2 < 32; k2++) acc = dot2acc(u2c[k2 * 256], h2p[k2], acc);
        zbuf[tid] = acc;
      }
      __syncthreads();
      if (tid < 64) {
        float gi = sigm(zbuf[tid]);
        float gf = sigm(zbuf[64 + tid]);
        float gg = reluf(zbuf[128 + tid]);
        float go = sigm(zbuf[192 + tid]);
        c2 = gf * c2 + gi * gg;
        float h = go * reluf(c2);
        float hn = __shfl_xor(h, 1);
        if ((tid & 1) == 0) h2p[tid >> 1] = packh2(h, hn);
        hfin[tid] = h;
      }
      __syncthreads();
    }
    if (tid < 128) {
      float acc = A.pd0b[tid];
      for (int k = 0; k < 64; k++) acc += hfin[k] * A.pd0W[k * 128 + tid];
      zbuf[tid] = reluf(acc);
    }
    __syncthreads();
    if (tid < 64) {
      float acc = A.pd1b[tid];
      for (int k = 0; k < 128; k++) acc += zbuf[k] * A.pd1W[k * 64 + tid];
      zbuf[512 + tid] = reluf(acc);
    }
    __syncthreads();
    if (tid < 32) {
      float acc = A.pd2b[tid];
      for (int k = 0; k < 64; k++) acc += zbuf[512 + k] * A.pd2W[k * 32 + tid];
      A.feat[s * 64 + 32 + tid] = acc;
    }
  } else {
    // ---------- title sequence s ----------
    const int s = blk - 128;
    if (tid < 64) h0p[tid] = 0u;
    if (tid < 32) h1p[tid] = 0u;
    float c0 = 0.f, c1 = 0.f;
    const float b1r = (tid < 256) ? A.tl1_b[tid] : 0.f;
    const unsigned int* u0c = A.U0t + tid;
    const unsigned int* w1c = A.W1t + tid;
    const unsigned int* u1c = A.U1t + tid;
    const f16* xrow = A.xtW + (long)s * 64 * 512;
    __syncthreads();
    for (int t = 0; t < 64; t++) {
      if (tid < 512) {
        float acc = (float)xrow[t * 512 + tid];
#pragma unroll 8
        for (int k2 = 0; k2 < 64; k2++) acc = dot2acc(u0c[k2 * 512], h0p[k2], acc);
        zbuf[tid] = acc;
      }
      __syncthreads();
      if (tid < 128) {
        float gi = sigm(zbuf[tid]);
        float gf = sigm(zbuf[128 + tid]);
        float gg = reluf(zbuf[256 + tid]);
        float go = sigm(zbuf[384 + tid]);
        c0 = gf * c0 + gi * gg;
        float h = go * reluf(c0);
        float hn = __shfl_xor(h, 1);
        if ((tid & 1) == 0) h0p[tid >> 1] = packh2(h, hn);
      }
      __syncthreads();
      if (tid < 256) {
        float acc = b1r;
#pragma unroll 8
        for (int k2 = 0; k2 < 64; k2++) acc = dot2acc(w1c[k2 * 256], h0p[k2], acc);
#pragma unroll 8
        for (int k2 = 0; k2 < 32; k2++) acc = dot2acc(u1c[k2 * 256], h1p[k2], acc);
        zbuf[tid] = acc;
      }
      __syncthreads();
      if (tid < 64) {
        float gi = sigm(zbuf[tid]);
        float gf = sigm(zbuf[64 + tid]);
        float gg = reluf(zbuf[128 + tid]);
        float go = sigm(zbuf[192 + tid]);
        c1 = gf * c1 + gi * gg;
        float h = go * reluf(c1);
        float hn = __shfl_xor(h, 1);
        if ((tid & 1) == 0) h1p[tid >> 1] = packh2(h, hn);
        hfin[tid] = h;
      }
      __syncthreads();
    }
    if (tid < 128) {
      float acc = A.td0b[tid];
      for (int k = 0; k < 64; k++) acc += hfin[k] * A.td0W[k * 128 + tid];
      zbuf[tid] = reluf(acc);
    }
    __syncthreads();
    if (tid < 64) {
      float acc = A.td1b[tid];
      for (int k = 0; k < 128; k++) acc += zbuf[k] * A.td1W[k * 64 + tid];
      zbuf[512 + tid] = reluf(acc);
    }
    __syncthreads();
    if (tid < 32) {
      float acc = A.td2b[tid];
      for (int k = 0; k < 64; k++) acc += zbuf[512 + k] * A.td2W[k * 32 + tid];
      A.feat[s * 64 + tid] = acc;
    }
  }
}

// ---------------- head: mean over N=16, 4 dense layers, sigmoid
__global__ __launch_bounds__(256) void head_kernel(const float* __restrict__ feat,
    const float* __restrict__ L0W, const float* __restrict__ L0b,
    const float* __restrict__ L1W, const float* __restrict__ L1b,
    const float* __restrict__ L2W, const float* __restrict__ L2b,
    const float* __restrict__ L3W, const float* __restrict__ L3b,
    float* __restrict__ out) {
  __shared__ float xb[512];
  __shared__ float y0[2048];
  __shared__ float y1[1024];
  __shared__ float y2[512];
  const int tid = threadIdx.x;
  for (int idx = tid; idx < 512; idx += 256) {
    int b = idx >> 6, d = idx & 63;
    float s = 0.f;
    for (int n = 0; n < 16; n++) s += feat[(b * 16 + n) * 64 + d];
    xb[idx] = s * (1.f / 16.f);
  }
  __syncthreads();
  for (int idx = tid; idx < 2048; idx += 256) {
    int b = idx >> 8, j = idx & 255;
    float a = L0b[j];
    for (int k = 0; k < 64; k++) a += xb[b * 64 + k] * L0W[k * 256 + j];
    y0[idx] = reluf(a);
  }
  __syncthreads();
  for (int idx = tid; idx < 1024; idx += 256) {
    int b = idx >> 7, j = idx & 127;
    float a = L1b[j];
    for (int k = 0; k < 256; k++) a += y0[b * 256 + k] * L1W[k * 128 + j];
    y1[idx] = reluf(a);
  }
  __syncthreads();
  for (int idx = tid; idx < 512; idx += 256) {
    int b = idx >> 6, j = idx & 63;
    float a = L2b[j];
    for (int k = 0; k < 128; k++) a += y1[b * 128 + k] * L2W[k * 64 + j];
    y2[idx] = reluf(a);
  }
  __syncthreads();
  {
    int b = tid >> 5, j = tid & 31;
    float a = L3b[j];
    for (int k = 0; k < 64; k++) a += y2[b * 64 + k] * L3W[k * 32 + j];
    out[b * 32 + j] = 1.f / (1.f + __expf(-a));
  }
}

extern "C" void kernel_launch(void* const* d_in, const int* in_sizes, int n_in,
                              void* d_out, int out_size, void* d_ws, size_t ws_size,
                              hipStream_t stream) {
  const int*   t_tok = (const int*)d_in[0];
  const int*   p_tok = (const int*)d_in[1];
  const float* emb_t = (const float*)d_in[2];
  const float* emb_p = (const float*)d_in[3];
  const float* tl0_W = (const float*)d_in[4];
  const float* tl0_U = (const float*)d_in[5];
  const float* tl0_b = (const float*)d_in[6];
  const float* tl1_W = (const float*)d_in[7];
  const float* tl1_U = (const float*)d_in[8];
  const float* tl1_b = (const float*)d_in[9];
  const float* td0_W = (const float*)d_in[10];
  const float* td0_b = (const float*)d_in[11];
  const float* td1_W = (const float*)d_in[12];
  const float* td1_b = (const float*)d_in[13];
  const float* td2_W = (const float*)d_in[14];
  const float* td2_b = (const float*)d_in[15];
  const float* pl0_W = (const float*)d_in[16];
  const float* pl0_U = (const float*)d_in[17];
  const float* pl0_b = (const float*)d_in[18];
  const float* pl1_W = (const float*)d_in[19];
  const float* pl1_U = (const float*)d_in[20];
  const float* pl1_b = (const float*)d_in[21];
  const float* pl2_W = (const float*)d_in[22];
  const float* pl2_U = (const float*)d_in[23];
  const float* pl2_b = (const float*)d_in[24];
  const float* pd0_W = (const float*)d_in[25];
  const float* pd0_b = (const float*)d_in[26];
  const float* pd1_W = (const float*)d_in[27];
  const float* pd1_b = (const float*)d_in[28];
  const float* pd2_W = (const float*)d_in[29];
  const float* pd2_b = (const float*)d_in[30];
  const float* L0_W  = (const float*)d_in[31];
  const float* L0_b  = (const float*)d_in[32];
  const float* L1_W  = (const float*)d_in[33];
  const float* L1_b  = (const float*)d_in[34];
  const float* L2_W  = (const float*)d_in[35];
  const float* L2_b  = (const float*)d_in[36];
  const float* L3_W  = (const float*)d_in[37];
  const float* L3_b  = (const float*)d_in[38];

  char* ws = (char*)d_ws;
  size_t off = 0;
  auto alloc = [&](size_t bytes) {
    void* ptr = ws + off;
    off += (bytes + 255) & ~(size_t)255;
    return ptr;
  };
  f16* xpW = (f16*)alloc((size_t)65536 * 1024 * 2);
  f16* xtW = (f16*)alloc((size_t)8192 * 512 * 2);
  f16* Bp  = (f16*)alloc((size_t)256 * 1024 * 2);
  f16* Bt  = (f16*)alloc((size_t)128 * 512 * 2);
  unsigned int* U0p = (unsigned int*)alloc((size_t)128 * 1024 * 4);
  unsigned int* W1p = (unsigned int*)alloc((size_t)128 * 512 * 4);
  unsigned int* U1p = (unsigned int*)alloc((size_t)64 * 512 * 4);
  unsigned int* W2p = (unsigned int*)alloc((size_t)64 * 256 * 4);
  unsigned int* U2p = (unsigned int*)alloc((size_t)32 * 256 * 4);
  unsigned int* U0t = (unsigned int*)alloc((size_t)64 * 512 * 4);
  unsigned int* W1t = (unsigned int*)alloc((size_t)64 * 256 * 4);
  unsigned int* U1t = (unsigned int*)alloc((size_t)32 * 256 * 4);
  float* feat = (float*)alloc((size_t)128 * 64 * 4);

  // pack recurrent weights (f16 pairs along K)
  pack_pairs<<<dim3(4, 128), 256, 0, stream>>>(pl0_U, U0p, 1024);
  pack_pairs<<<dim3(2, 128), 256, 0, stream>>>(pl1_W, W1p, 512);
  pack_pairs<<<dim3(2, 64),  256, 0, stream>>>(pl1_U, U1p, 512);
  pack_pairs<<<dim3(1, 64),  256, 0, stream>>>(pl2_W, W2p, 256);
  pack_pairs<<<dim3(1, 32),  256, 0, stream>>>(pl2_U, U2p, 256);
  pack_pairs<<<dim3(2, 64),  256, 0, stream>>>(tl0_U, U0t, 512);
  pack_pairs<<<dim3(1, 64),  256, 0, stream>>>(tl1_W, W1t, 256);
  pack_pairs<<<dim3(1, 32),  256, 0, stream>>>(tl1_U, U1t, 256);
  // pack GEMM B operands into MFMA fragment layout
  pack_bsw<8><<<1024, 256, 0, stream>>>(pl0_W, Bp, 1024);
  pack_bsw<4><<<256, 256, 0, stream>>>(tl0_W, Bt, 512);
  // xW + b precompute (gathers embeddings internally)
  gemm_xw<256, 8, 1024, 64><<<1024, 256, 0, stream>>>(p_tok, emb_p, Bp, pl0_b, xpW);
  gemm_xw<128, 4, 512, 32><<<128, 256, 0, stream>>>(t_tok, emb_t, Bt, tl0_b, xtW);

  RecurArgs ra;
  ra.xpW = xpW; ra.xtW = xtW;
  ra.U0p = U0p; ra.W1p = W1p; ra.U1p = U1p; ra.W2p = W2p; ra.U2p = U2p;
  ra.U0t = U0t; ra.W1t = W1t; ra.U1t = U1t;
  ra.pl1_b = pl1_b; ra.pl2_b = pl2_b; ra.tl1_b = tl1_b;
  ra.pd0W = pd0_W; ra.pd0b = pd0_b; ra.pd1W = pd1_W; ra.pd1b = pd1_b;
  ra.pd2W = pd2_W; ra.pd2b = pd2_b;
  ra.td0W = td0_W; ra.td0b = td0_b; ra.td1W = td1_W; ra.td1b = td1_b;
  ra.td2W = td2_W; ra.td2b = td2_b;
  ra.feat = feat;
  recur_kernel<<<256, 1024, 0, stream>>>(ra);

  head_kernel<<<1, 256, 0, stream>>>(feat, L0_W, L0_b, L1_W, L1_b, L2_W, L2_b,
                                     L3_W, L3_b, (float*)d_out);
}